// Round 2
// baseline (7970.382 us; speedup 1.0000x reference)
//
#include <hip/hip_runtime.h>
#include <cmath>

// ---------------- problem constants ----------------
#define B_SZ 32
#define T_SZ 96
#define N_SZ 128
#define DM   64
#define K_PAD 144      // padded K (129 real cols -> 4x32 + 1x16 MFMA k-steps)

typedef _Float16 half_t;
typedef _Float16 h8_t __attribute__((ext_vector_type(8)));
typedef _Float16 h4_t __attribute__((ext_vector_type(4)));
typedef float    f4_t __attribute__((ext_vector_type(4)));

// legacy-named builtin for the K=16 tail step (gfx950 keeps CDNA2 spelling)
#define MFMA16x16x16(a, b, c) __builtin_amdgcn_mfma_f32_16x16x16f16((a), (b), (c), 0, 0, 0)
#define MFMA16x16x32(a, b, c) __builtin_amdgcn_mfma_f32_16x16x32_f16((a), (b), (c), 0, 0, 0)

// LDS strides (elements). Chosen for 16B alignment of b128/b64 frag reads and
// low bank conflict (stride*2 bytes: 304,272,272,80 -> start-bank walks are >=2-way-free).
#define SC_STRIDE  152   // s_comb / s_cc   [128][152]
#define SCT_STRIDE 136   // s_combT         [144][136]
#define ATT_STRIDE 136   // s_att           [128][136]
#define QK_STRIDE   40   // s_qk            [128][40] (overlay on s_cc)

// LDS offsets (bytes), all 16B aligned; total 156416 <= 163840
#define OFF_COMB   0
#define OFF_COMBT  38912
#define OFF_CC     78080
#define OFF_ATT    116992
#define OFF_QV     151808
#define OFF_MASK   155904
#define LDS_BYTES  156416

// ws offsets (bytes)
#define WS_BTG   0          // fp16 [960][144]  (g=0:r, 1:u, 2:cand) rows = g*320 + d*64 + o
#define WS_BTQK  276480     // fp16 [32][144]   cols 0..15 q, 16..31 k
#define WS_QV    285696     // f32  [128][8]
#define WS_VT    289792     // f32  [32][128]
#define WS_RSC   306176     // f32  [32][96][128]

// ---------------- precompute kernels ----------------

__global__ void k_var(const int* __restrict__ mask, float* __restrict__ vt) {
    int i = blockIdx.x * 256 + threadIdx.x;          // B*N = 4096
    if (i >= B_SZ * N_SZ) return;
    int b = i >> 7, n = i & 127;
    float s = 0.f;
    for (int t = 0; t < T_SZ; ++t) s += (float)mask[(b * T_SZ + t) * N_SZ + n];
    vt[i] = s;
}

__global__ void k_rsc(const float* __restrict__ ai, const float* __restrict__ vt,
                      float* __restrict__ rsc) {
    int i = blockIdx.x * 256 + threadIdx.x;          // B*T*N
    if (i >= B_SZ * T_SZ * N_SZ) return;
    int b = i / (T_SZ * N_SZ);
    int n = i & 127;
    rsc[i] = 0.5f * tanhf(ai[i] / (vt[b * N_SZ + n] + 1.f));
}

// qv[n,0..4] = relu(plm[n]@W1 + b1)@W2 + b2   (batch-independent)
__global__ void k_qv(const float* __restrict__ plm, const float* __restrict__ W1,
                     const float* __restrict__ b1, const float* __restrict__ W2,
                     const float* __restrict__ b2, float* __restrict__ qvw) {
    __shared__ float hid[128];
    int n = blockIdx.x;
    int t = threadIdx.x;
    if (t < 128) {
        float acc = b1[t];
        for (int j = 0; j < 768; ++j) acc += plm[n * 768 + j] * W1[j * 128 + t];
        hid[t] = fmaxf(acc, 0.f);
    }
    __syncthreads();
    if (t < 8) {
        float v = 0.f;
        if (t < 5) {
            float acc = b2[t];
            for (int j = 0; j < 128; ++j) acc += hid[j] * W2[j * 5 + t];
            v = acc;
        }
        qvw[n * 8 + t] = v;
    }
}

// Bt_qk[c][k]: k<=128 -> Wq/Wk[k][c&15]; k==129 -> bias; else 0
__global__ void k_btqk(const float* __restrict__ Wq, const float* __restrict__ bq,
                       const float* __restrict__ Wk, const float* __restrict__ bk,
                       half_t* __restrict__ o) {
    int i = blockIdx.x * 256 + threadIdx.x;
    if (i >= 32 * K_PAD) return;
    int c = i / K_PAD, k = i % K_PAD;
    int cc = c & 15;
    float v = 0.f;
    if (k <= 128) v = (c < 16) ? Wq[k * 16 + cc] : Wk[k * 16 + cc];
    else if (k == 129) v = (c < 16) ? bq[cc] : bk[cc];
    o[i] = (half_t)v;
}

// r/u gate weights: M_d = Wv @ gW[d]  (fold Wv into hypernet), bias row at k=129
__global__ void k_btg(const float* __restrict__ Wv, const float* __restrict__ bv,
                      const float* __restrict__ rgW, const float* __restrict__ rgb,
                      const float* __restrict__ ugW, const float* __restrict__ ugb,
                      half_t* __restrict__ btg) {
    __shared__ float shw[129 * 64];
    __shared__ float shb[64];
    int g = blockIdx.x / 5, d = blockIdx.x % 5;
    const float* gw = (g == 0) ? rgW : ugW;
    const float* gb = (g == 0) ? rgb : ugb;
    for (int i = threadIdx.x; i < 129 * 64; i += 256) shw[i] = gw[d * 129 * 64 + i];
    __syncthreads();
    if (threadIdx.x < 64) {
        int o = threadIdx.x;
        float acc = gb[d * 64 + o];
        for (int i = 0; i < 129; ++i) acc += bv[i] * shw[i * 64 + o];
        shb[o] = acc;
    }
    __syncthreads();
    int o = threadIdx.x & 63, kq = threadIdx.x >> 6;
    for (int k = kq; k < K_PAD; k += 4) {
        float v;
        if (k <= 128) {
            float acc = 0.f;
            for (int i = 0; i < 129; ++i) acc += Wv[k * 129 + i] * shw[i * 64 + o];
            v = acc;
        } else if (k == 129) v = shb[o];
        else v = 0.f;
        btg[(size_t)(g * 320 + d * 64 + o) * K_PAD + k] = (half_t)v;
    }
}

// cand gate weights: direct copy of cg_W (no Wv), bias at k=129
__global__ void k_btc(const float* __restrict__ cgW, const float* __restrict__ cgb,
                      half_t* __restrict__ btg) {
    int i = blockIdx.x * 256 + threadIdx.x;
    if (i >= 320 * K_PAD) return;
    int c = i / K_PAD, k = i % K_PAD;
    int d = c >> 6, o = c & 63;
    float v = 0.f;
    if (k <= 128) v = cgW[(d * 129 + k) * 64 + o];
    else if (k == 129) v = cgb[d * 64 + o];
    btg[(size_t)(640 + c) * K_PAD + k] = (half_t)v;
}

// ---------------- main recurrent kernel ----------------
// One block per batch; 1024 threads = 16 waves; T-loop inside.
// comb = [x(0..63), r_sc(64), h(65..128), 1.0(129), 0(130..143)] fp16
// cc   = att @ comb  (col 129 = sum(att) ~= 1 -> bias rider)
// gates: pre[n,o] = sum_d qv[n,d] * (A @ Bt_g[d])[n,o]   (d-major tiles -> in-register contraction)

__global__ __launch_bounds__(1024) void kedgn_main(
    const float* __restrict__ obs,      // [B,T,N,64]
    const float* __restrict__ rscp,     // [B,T,N]
    const int* __restrict__ maskI,      // [B,T,N]
    const int* __restrict__ lengths,    // [B,1]
    const half_t* __restrict__ btqk,    // [32][144]
    const half_t* __restrict__ btg,     // [960][144]
    const float* __restrict__ qvw,      // [128][8]
    float* __restrict__ out)            // [B,128,64]
{
    extern __shared__ char smem[];
    half_t* s_comb  = (half_t*)(smem + OFF_COMB);
    half_t* s_combT = (half_t*)(smem + OFF_COMBT);
    half_t* s_cc    = (half_t*)(smem + OFF_CC);
    half_t* s_att   = (half_t*)(smem + OFF_ATT);
    float*  s_qv    = (float*)(smem + OFF_QV);
    float*  s_mask  = (float*)(smem + OFF_MASK);
    half_t* s_qk    = s_cc;   // overlay: q/k live only between G1 and G3

    const int b    = blockIdx.x;
    const int tid  = threadIdx.x;
    const int lane = tid & 63;
    const int w    = tid >> 6;     // wave 0..15
    const int r16  = lane & 15;
    const int g4   = lane >> 4;    // 0..3
    const int tm   = w >> 1;       // output row-tile 0..7
    const int og   = w & 1;        // output col-half

    // ---- init LDS (every launch; harness does not reset LDS) ----
    for (int i = tid; i < 128 * SC_STRIDE; i += 1024) {
        int c = i % SC_STRIDE;
        s_comb[i] = (c == 129) ? (half_t)1.f : (half_t)0.f;   // bias-1 col
    }
    for (int i = tid; i < K_PAD * SCT_STRIDE; i += 1024) {
        int r = i / SCT_STRIDE;
        s_combT[i] = (r == 129) ? (half_t)1.f : (half_t)0.f;  // ones row -> cc col129 = sum(att)
    }
    for (int i = tid; i < 128 * 8; i += 1024) s_qv[i] = qvw[i];

    const int idx = min(max(lengths[b] - 1, 0), T_SZ - 1);

    float hreg[2][4];   // h for this lane's (row = tm*16+g4*4+r, o = (og*2+sub)*16+r16)
    float ureg[2][4], hrreg[2][4], cnd[2][4];
    #pragma unroll
    for (int s = 0; s < 2; ++s)
        #pragma unroll
        for (int r = 0; r < 4; ++r) hreg[s][r] = 0.f;

    __syncthreads();

    for (int t = 0; t < T_SZ; ++t) {
        // ---------- Phase A: build x-part of comb / combT, masks ----------
        {
            const int n = tid >> 3, dg = tid & 7;
            const float4* src = (const float4*)(obs +
                (((size_t)b * T_SZ + t) * N_SZ + n) * 64 + dg * 8);
            float4 v0 = src[0], v1 = src[1];
            half_t hv[8] = {(half_t)v0.x,(half_t)v0.y,(half_t)v0.z,(half_t)v0.w,
                            (half_t)v1.x,(half_t)v1.y,(half_t)v1.z,(half_t)v1.w};
            *(h8_t*)&s_comb[n * SC_STRIDE + dg * 8] = *(h8_t*)hv;
            #pragma unroll
            for (int i = 0; i < 8; ++i) s_combT[(dg * 8 + i) * SCT_STRIDE + n] = hv[i];
            if (tid < 128) {
                float rv = rscp[((size_t)b * T_SZ + t) * N_SZ + tid];
                s_comb[tid * SC_STRIDE + 64]  = (half_t)rv;
                s_combT[64 * SCT_STRIDE + tid] = (half_t)rv;
                s_mask[tid] = (float)maskI[((size_t)b * T_SZ + t) * N_SZ + tid];
            }
        }
        __syncthreads();

        // ---------- G1: q,k = comb @ Wqk (+bias via col129) ----------
        {
            const int ct = og;   // 0:q 1:k
            f4_t acc = {0.f, 0.f, 0.f, 0.f};
            #pragma unroll
            for (int ik = 0; ik < 4; ++ik) {
                int kk = ik * 32;
                h8_t a = *(const h8_t*)&s_comb[(tm * 16 + r16) * SC_STRIDE + kk + g4 * 8];
                h8_t bf = *(const h8_t*)&btqk[(ct * 16 + r16) * K_PAD + kk + g4 * 8];
                acc = MFMA16x16x32(a, bf, acc);
            }
            {
                h4_t a = *(const h4_t*)&s_comb[(tm * 16 + r16) * SC_STRIDE + 128 + g4 * 4];
                h4_t bf = *(const h4_t*)&btqk[(ct * 16 + r16) * K_PAD + 128 + g4 * 4];
                acc = MFMA16x16x16(a, bf, acc);
            }
            #pragma unroll
            for (int r = 0; r < 4; ++r)
                s_qk[(tm * 16 + g4 * 4 + r) * QK_STRIDE + ct * 16 + r16] = (half_t)acc[r];
        }
        __syncthreads();

        // ---------- G2: sc = q@k^T /4, leaky(0.2), mask -> s_att fp16 ----------
        {
            float mrow[4];
            #pragma unroll
            for (int r = 0; r < 4; ++r) mrow[r] = s_mask[tm * 16 + g4 * 4 + r];
            #pragma unroll
            for (int c = 0; c < 4; ++c) {
                int ct = og * 4 + c;
                h4_t a  = *(const h4_t*)&s_qk[(tm * 16 + r16) * QK_STRIDE + g4 * 4];
                h4_t bf = *(const h4_t*)&s_qk[(ct * 16 + r16) * QK_STRIDE + 16 + g4 * 4];
                f4_t acc = {0.f, 0.f, 0.f, 0.f};
                acc = MFMA16x16x16(a, bf, acc);
                int m = ct * 16 + r16;
                float mcol = s_mask[m];
                #pragma unroll
                for (int r = 0; r < 4; ++r) {
                    int n = tm * 16 + g4 * 4 + r;
                    float v = acc[r] * 0.25f;
                    v = (v < 0.f) ? 0.2f * v : v;
                    bool allowed = (n == m) || (mrow[r] > 0.f && mcol > 0.f);
                    s_att[n * ATT_STRIDE + m] = allowed ? (half_t)v : (half_t)(-INFINITY);
                }
            }
        }
        __syncthreads();

        // ---------- softmax rows (8 lanes per row) ----------
        {
            int row = w * 8 + (lane >> 3);
            int cg  = lane & 7;
            half_t* ap = &s_att[row * ATT_STRIDE + cg * 16];
            h8_t v0 = *(const h8_t*)ap;
            h8_t v1 = *(const h8_t*)(ap + 8);
            float v[16];
            #pragma unroll
            for (int i = 0; i < 8; ++i) { v[i] = (float)v0[i]; v[8 + i] = (float)v1[i]; }
            float mx = v[0];
            #pragma unroll
            for (int i = 1; i < 16; ++i) mx = fmaxf(mx, v[i]);
            mx = fmaxf(mx, __shfl_xor(mx, 1));
            mx = fmaxf(mx, __shfl_xor(mx, 2));
            mx = fmaxf(mx, __shfl_xor(mx, 4));
            float e[16], sum = 0.f;
            #pragma unroll
            for (int i = 0; i < 16; ++i) { e[i] = expf(v[i] - mx); sum += e[i]; }
            sum += __shfl_xor(sum, 1);
            sum += __shfl_xor(sum, 2);
            sum += __shfl_xor(sum, 4);
            float rs = 1.f / sum;
            h8_t o0, o1;
            #pragma unroll
            for (int i = 0; i < 8; ++i) { o0[i] = (half_t)(e[i] * rs); o1[i] = (half_t)(e[8 + i] * rs); }
            *(h8_t*)ap = o0;
            *(h8_t*)(ap + 8) = o1;
        }
        __syncthreads();

        // ---------- G3: cc = att @ comb  (B from combT), overwrites qk region ----------
        {
            int ct0 = (og == 0) ? 0 : 5;
            int nct = (og == 0) ? 5 : 4;
            for (int ci = 0; ci < nct; ++ci) {
                int ct = ct0 + ci;
                f4_t acc = {0.f, 0.f, 0.f, 0.f};
                #pragma unroll
                for (int ik = 0; ik < 4; ++ik) {
                    int kk = ik * 32;
                    h8_t a  = *(const h8_t*)&s_att[(tm * 16 + r16) * ATT_STRIDE + kk + g4 * 8];
                    h8_t bf = *(const h8_t*)&s_combT[(ct * 16 + r16) * SCT_STRIDE + kk + g4 * 8];
                    acc = MFMA16x16x32(a, bf, acc);
                }
                #pragma unroll
                for (int r = 0; r < 4; ++r)
                    s_cc[(tm * 16 + g4 * 4 + r) * SC_STRIDE + ct * 16 + r16] = (half_t)acc[r];
            }
        }
        __syncthreads();

        // ---------- G4 r (g=0) and u (g=1): A = cc, in-register qv contraction ----------
        for (int g = 0; g < 2; ++g) {
            #pragma unroll
            for (int sub = 0; sub < 2; ++sub) {
                int oi = og * 2 + sub;
                f4_t acc[5];
                #pragma unroll
                for (int d = 0; d < 5; ++d) acc[d] = (f4_t){0.f, 0.f, 0.f, 0.f};
                #pragma unroll
                for (int ik = 0; ik < 4; ++ik) {
                    int kk = ik * 32;
                    h8_t a = *(const h8_t*)&s_cc[(tm * 16 + r16) * SC_STRIDE + kk + g4 * 8];
                    #pragma unroll
                    for (int d = 0; d < 5; ++d) {
                        h8_t bf = *(const h8_t*)&btg[(g * 320 + d * 64 + oi * 16 + r16) * K_PAD + kk + g4 * 8];
                        acc[d] = MFMA16x16x32(a, bf, acc[d]);
                    }
                }
                {
                    h4_t a = *(const h4_t*)&s_cc[(tm * 16 + r16) * SC_STRIDE + 128 + g4 * 4];
                    #pragma unroll
                    for (int d = 0; d < 5; ++d) {
                        h4_t bf = *(const h4_t*)&btg[(g * 320 + d * 64 + oi * 16 + r16) * K_PAD + 128 + g4 * 4];
                        acc[d] = MFMA16x16x16(a, bf, acc[d]);
                    }
                }
                #pragma unroll
                for (int r = 0; r < 4; ++r) {
                    int row = tm * 16 + g4 * 4 + r;
                    float pre = 0.f;
                    #pragma unroll
                    for (int d = 0; d < 5; ++d) pre += s_qv[row * 8 + d] * acc[d][r];
                    float sv = 1.f / (1.f + expf(-pre));
                    if (g == 0) {
                        float hv  = hreg[sub][r];
                        float hrv = (s_mask[row] > 0.f) ? sv * hv : hv;
                        hrreg[sub][r] = hrv;
                        s_comb[row * SC_STRIDE + 65 + oi * 16 + r16] = (half_t)hrv;  // comb -> combc
                    } else {
                        ureg[sub][r] = sv;
                    }
                }
            }
        }
        __syncthreads();   // h_r visible in comb before cand GEMM

        // ---------- G4c: cand = tanh( combc @ Bt_c ) -- compute only ----------
        #pragma unroll
        for (int sub = 0; sub < 2; ++sub) {
            int oi = og * 2 + sub;
            f4_t acc[5];
            #pragma unroll
            for (int d = 0; d < 5; ++d) acc[d] = (f4_t){0.f, 0.f, 0.f, 0.f};
            #pragma unroll
            for (int ik = 0; ik < 4; ++ik) {
                int kk = ik * 32;
                h8_t a = *(const h8_t*)&s_comb[(tm * 16 + r16) * SC_STRIDE + kk + g4 * 8];
                #pragma unroll
                for (int d = 0; d < 5; ++d) {
                    h8_t bf = *(const h8_t*)&btg[(640 + d * 64 + oi * 16 + r16) * K_PAD + kk + g4 * 8];
                    acc[d] = MFMA16x16x32(a, bf, acc[d]);
                }
            }
            {
                h4_t a = *(const h4_t*)&s_comb[(tm * 16 + r16) * SC_STRIDE + 128 + g4 * 4];
                #pragma unroll
                for (int d = 0; d < 5; ++d) {
                    h4_t bf = *(const h4_t*)&btg[(640 + d * 64 + oi * 16 + r16) * K_PAD + 128 + g4 * 4];
                    acc[d] = MFMA16x16x16(a, bf, acc[d]);
                }
            }
            #pragma unroll
            for (int r = 0; r < 4; ++r) {
                int row = tm * 16 + g4 * 4 + r;
                float pre = 0.f;
                #pragma unroll
                for (int d = 0; d < 5; ++d) pre += s_qv[row * 8 + d] * acc[d][r];
                cnd[sub][r] = tanhf(pre);
            }
        }
        __syncthreads();   // all cand A-reads done before overwriting h cols

        // ---------- blend + write h back (and output snapshot) ----------
        #pragma unroll
        for (int sub = 0; sub < 2; ++sub) {
            int oi = og * 2 + sub;
            int o  = oi * 16 + r16;
            #pragma unroll
            for (int r = 0; r < 4; ++r) {
                int row = tm * 16 + g4 * 4 + r;
                float hv = hreg[sub][r], hrv = hrreg[sub][r], uv = ureg[sub][r];
                float nh = (1.f - uv) * hrv + uv * cnd[sub][r];
                float hout = (s_mask[row] > 0.f) ? nh : hv;
                hreg[sub][r] = hout;
                s_comb[row * SC_STRIDE + 65 + o] = (half_t)hout;
                s_combT[(65 + o) * SCT_STRIDE + row] = (half_t)hout;
                if (t == idx) out[((size_t)b * N_SZ + row) * 64 + o] = hout;
            }
        }
        __syncthreads();   // protect comb/combT before next step
    }
}

// ---------------- host launcher ----------------
extern "C" void kernel_launch(void* const* d_in, const int* in_sizes, int n_in,
                              void* d_out, int out_size, void* d_ws, size_t ws_size,
                              hipStream_t stream) {
    const float* obs   = (const float*)d_in[0];
    const float* ai    = (const float*)d_in[1];
    const float* plm   = (const float*)d_in[2];
    // d_in[3] rarity_W: unused (only cur_adj==0 matters; adj=softmax>0 strictly)
    const float* pfW1  = (const float*)d_in[4];
    const float* pfb1  = (const float*)d_in[5];
    const float* pfW2  = (const float*)d_in[6];
    const float* pfb2  = (const float*)d_in[7];
    // d_in[8..11] pg_*: unused (emb/adj only affect masking, which reduces to observed_mask)
    const float* Wq    = (const float*)d_in[12];
    const float* bq    = (const float*)d_in[13];
    const float* Wk    = (const float*)d_in[14];
    const float* bk    = (const float*)d_in[15];
    const float* Wv    = (const float*)d_in[16];
    const float* bv    = (const float*)d_in[17];
    const float* ugW   = (const float*)d_in[18];
    const float* ugb   = (const float*)d_in[19];
    const float* rgW   = (const float*)d_in[20];
    const float* rgb   = (const float*)d_in[21];
    const float* cgW   = (const float*)d_in[22];
    const float* cgb   = (const float*)d_in[23];
    const int* maskI   = (const int*)d_in[24];
    const int* lengths = (const int*)d_in[25];

    char* ws = (char*)d_ws;
    half_t* btg  = (half_t*)(ws + WS_BTG);
    half_t* btqk = (half_t*)(ws + WS_BTQK);
    float*  qvw  = (float*)(ws + WS_QV);
    float*  vt   = (float*)(ws + WS_VT);
    float*  rscp = (float*)(ws + WS_RSC);

    hipLaunchKernelGGL(k_var, dim3(16), dim3(256), 0, stream, maskI, vt);
    hipLaunchKernelGGL(k_rsc, dim3((B_SZ * T_SZ * N_SZ + 255) / 256), dim3(256), 0, stream,
                       ai, vt, rscp);
    hipLaunchKernelGGL(k_qv, dim3(128), dim3(256), 0, stream, plm, pfW1, pfb1, pfW2, pfb2, qvw);
    hipLaunchKernelGGL(k_btqk, dim3((32 * K_PAD + 255) / 256), dim3(256), 0, stream,
                       Wq, bq, Wk, bk, btqk);
    hipLaunchKernelGGL(k_btg, dim3(10), dim3(256), 0, stream, Wv, bv, rgW, rgb, ugW, ugb, btg);
    hipLaunchKernelGGL(k_btc, dim3((320 * K_PAD + 255) / 256), dim3(256), 0, stream,
                       cgW, cgb, btg);

    (void)hipFuncSetAttribute((const void*)kedgn_main,
                              hipFuncAttributeMaxDynamicSharedMemorySize, LDS_BYTES);
    hipLaunchKernelGGL(kedgn_main, dim3(B_SZ), dim3(1024), LDS_BYTES, stream,
                       obs, rscp, maskI, lengths, btqk, btg, qvw, (float*)d_out);
}